// Round 11
// baseline (45.606 us; speedup 1.0000x reference)
//
#include <hip/hip_runtime.h>

typedef short bf16x8 __attribute__((ext_vector_type(8)));
typedef float f32x16 __attribute__((ext_vector_type(16)));
typedef float f32x4  __attribute__((ext_vector_type(4)));

#define BATCH    8
#define NPTS     8192
#define THREADS  256
#define NQ_TOTAL (BATCH * 2 * NPTS)   // 131072
#define TSPLIT   8
#define TSLICE   (NPTS / TSPLIT)      // 1024 targets per block (16 KB LDS)
#define NJ       4                    // query groups per wave (128 queries/wave)
#define RTHREADS 1024                 // reduce kernel block size

__device__ __forceinline__ unsigned short f2bf(float f) {   // fp32 -> bf16 RNE
    unsigned u = __builtin_bit_cast(unsigned, f);
    u += 0x7FFFu + ((u >> 16) & 1u);
    return (unsigned short)(u >> 16);
}
__device__ __forceinline__ float bf2f(unsigned short h) {
    return __builtin_bit_cast(float, (unsigned)h << 16);
}

// Pack every point (both arrays) into its 8-bf16 target fragment:
// [xh, yh, zh, xl, yl, zl, bbh, bbl]; also init minq[i] = +huge.
__global__ __launch_bounds__(THREADS) void chamfer_pack(
    const float* __restrict__ A, const float* __restrict__ Bp,
    short* __restrict__ pk, float* __restrict__ minq)
{
    const int i = blockIdx.x * THREADS + threadIdx.x;          // 0..131071
    const float* p = (i < BATCH * NPTS) ? (A + (size_t)i * 3)
                                        : (Bp + (size_t)(i - BATCH * NPTS) * 3);
    const float x = p[0], y = p[1], z = p[2];
    const unsigned short xh = f2bf(x), yh = f2bf(y), zh = f2bf(z);
    const unsigned short xl = f2bf(x - bf2f(xh));
    const unsigned short yl = f2bf(y - bf2f(yh));
    const unsigned short zl = f2bf(z - bf2f(zh));
    const float bb = fmaf(z, z, fmaf(y, y, x * x));
    const unsigned short bh = f2bf(bb);
    const unsigned short bl = f2bf(bb - bf2f(bh));
    bf16x8 v = {(short)xh, (short)yh, (short)zh, (short)xl,
                (short)yl, (short)zl, (short)bh, (short)bl};
    ((bf16x8*)pk)[i] = v;
    minq[i] = 3.4e38f;
}

// Stage 1: each wave owns 128 queries (4 col-groups of 32) and one
// 1024-target slice (staged once in LDS). One 32x32x16 bf16 MFMA per
// (32-target tile x 32-query group): D[t][q] = bb_t - 2 a_q.b_t
// (split-bf16, error ~3e-5). Min via fminf chains (compiler fuses to
// v_min3_f32 and handles MFMA->VALU hazards; no inline asm on MFMA dests).
// __launch_bounds__(256,4): cap VGPR at 128 so 4 blocks/CU stay resident
// while keeping acc in arch VGPRs (not AGPRs -- R8's VGPR=28 disease).
__global__ __launch_bounds__(THREADS, 4) void chamfer_stage1(
    const float* __restrict__ A, const float* __restrict__ Bp,
    const short* __restrict__ pk, float* __restrict__ minq)
{
    __shared__ short lds[TSLICE * 8];

    const int bid    = blockIdx.x;          // 2048 blocks
    const int ts     = bid & (TSPLIT - 1);  // 3 bits
    const int qchunk = (bid >> 3) & 15;     // 4 bits
    const int bd     = bid >> 7;            // 0..15
    const int b      = bd >> 1, dir = bd & 1;

    const float*  Q    = (dir == 0) ? (A + (size_t)b * NPTS * 3)
                                    : (Bp + (size_t)b * NPTS * 3);
    const bf16x8* tsrc = (const bf16x8*)pk +
                         (dir == 0 ? (BATCH * NPTS + b * NPTS) : (b * NPTS));

    const int tid  = threadIdx.x;
    const int wave = tid >> 6, lane = tid & 63;
    const int col  = lane & 31, g = lane >> 5;
    const int qbase = qchunk * 512 + wave * 128;

    // Stage this block's target slice (SoA frags) into LDS.
    bf16x8* ldsv = (bf16x8*)lds;
    const int sbase = ts * TSLICE;
#pragma unroll
    for (int u = 0; u < TSLICE / THREADS; ++u) {
        const int idx = u * THREADS + tid;
        ldsv[idx] = tsrc[sbase + idx];
    }

    // Per-lane query (B-side) fragments for the four 32-query groups.
    bf16x8 qf[NJ]; float aa[NJ];
#pragma unroll
    for (int j = 0; j < NJ; ++j) {
        const int q  = qbase + j * 32 + col;
        const float x = Q[q * 3 + 0], y = Q[q * 3 + 1], z = Q[q * 3 + 2];
        aa[j] = fmaf(z, z, fmaf(y, y, x * x));
        const float sx = -2.f * x, sy = -2.f * y, sz = -2.f * z;
        const unsigned short xh = f2bf(sx), yh = f2bf(sy), zh = f2bf(sz);
        const unsigned short xl = f2bf(sx - bf2f(xh));
        const unsigned short yl = f2bf(sy - bf2f(yh));
        const unsigned short zl = f2bf(sz - bf2f(zh));
        const short ONE = (short)0x3F80;          // bf16 1.0
        bf16x8 v0 = {(short)xh, (short)yh, (short)zh,
                     (short)xh, (short)yh, (short)zh, ONE, ONE};
        bf16x8 v1 = {(short)xl, (short)yl, (short)zl, 0, 0, 0, 0, 0};
        qf[j] = g ? v1 : v0;
    }

    const f32x16 kZero = {0.f,0.f,0.f,0.f,0.f,0.f,0.f,0.f,
                          0.f,0.f,0.f,0.f,0.f,0.f,0.f,0.f};   // hoisted C

    float mnA[NJ], mnB[NJ];
#pragma unroll
    for (int j = 0; j < NJ; ++j) { mnA[j] = 3.4e38f; mnB[j] = 3.4e38f; }

    __syncthreads();

#pragma unroll 2
    for (int t = 0; t < TSLICE / 32; ++t) {
        const bf16x8 af = ldsv[t * 32 + col];     // ds_read_b128 (2-lane alias, free)
#pragma unroll
        for (int j = 0; j < NJ; ++j) {
            f32x16 acc = __builtin_amdgcn_mfma_f32_32x32x16_bf16(
                af, qf[j], kZero, 0, 0, 0);
            mnA[j] = fminf(fminf(acc[0],  acc[1]),  mnA[j]);   // -> v_min3_f32
            mnA[j] = fminf(fminf(acc[2],  acc[3]),  mnA[j]);
            mnA[j] = fminf(fminf(acc[4],  acc[5]),  mnA[j]);
            mnA[j] = fminf(fminf(acc[6],  acc[7]),  mnA[j]);
            mnB[j] = fminf(fminf(acc[8],  acc[9]),  mnB[j]);
            mnB[j] = fminf(fminf(acc[10], acc[11]), mnB[j]);
            mnB[j] = fminf(fminf(acc[12], acc[13]), mnB[j]);
            mnB[j] = fminf(fminf(acc[14], acc[15]), mnB[j]);
        }
    }

#pragma unroll
    for (int j = 0; j < NJ; ++j) {
        float m = fminf(mnA[j], mnB[j]);
        m = fminf(m, __shfl_xor(m, 32, 64));      // merge row-halves
        if (g == 0)
            atomicMin((int*)&minq[bd * NPTS + qbase + j * 32 + col],
                      __float_as_int(m + aa[j]));
    }
}

// Final reduce: one block, 1024 threads, fixed per-thread accumulation
// order + wave/LDS tree -> deterministic sum of 131072 mins.
__global__ __launch_bounds__(RTHREADS) void chamfer_reduce(
    const float* __restrict__ minq, float* __restrict__ out)
{
    const f32x4* v4 = (const f32x4*)minq;          // 32768 float4s
    float s = 0.f;
#pragma unroll 8
    for (int i = 0; i < NQ_TOTAL / 4 / RTHREADS; ++i) {   // 32 each
        const f32x4 v = v4[i * RTHREADS + threadIdx.x];
        s += (v.x + v.y) + (v.z + v.w);
    }
#pragma unroll
    for (int off = 32; off; off >>= 1) s += __shfl_down(s, off, 64);

    __shared__ float wsum[RTHREADS / 64];
    if ((threadIdx.x & 63) == 0) wsum[threadIdx.x >> 6] = s;
    __syncthreads();
    if (threadIdx.x == 0) {
        float t = 0.f;
#pragma unroll
        for (int w = 0; w < RTHREADS / 64; ++w) t += wsum[w];
        out[0] = t;
    }
}

extern "C" void kernel_launch(void* const* d_in, const int* in_sizes, int n_in,
                              void* d_out, int out_size, void* d_ws, size_t ws_size,
                              hipStream_t stream) {
    const float* A  = (const float*)d_in[0];   // "input"  [8,8192,3]
    const float* Bp = (const float*)d_in[1];   // "output" [8,8192,3]
    float* out = (float*)d_out;

    short* pk   = (short*)d_ws;                                   // 2 MB packed frags
    float* minq = (float*)((char*)d_ws + (size_t)NQ_TOTAL * 16);  // 512 KB

    chamfer_pack<<<NQ_TOTAL / THREADS, THREADS, 0, stream>>>(A, Bp, pk, minq); // 512

    const int nblocks1 = BATCH * 2 * 16 * TSPLIT;                              // 2048
    chamfer_stage1<<<nblocks1, THREADS, 0, stream>>>(A, Bp, pk, minq);

    chamfer_reduce<<<1, RTHREADS, 0, stream>>>(minq, out);
}